// Round 1
// 580.381 us; speedup vs baseline: 1.1857x; 1.1857x over previous
//
#include <hip/hip_runtime.h>
#include <math.h>

#define BATCH 1024
#define T 500
#define K 20
#define D 256
#define H 51
#define ME 512

#define COEF 0.3989422917366028f
#define EPS 1e-5f
#define ALIGN_C 0.05f
// c_t truncation threshold: skipped terms contribute <= 500 * 1e-9 * |ctx|max
// ~ 2.5e-6 total error, vs harness-passing absmax of 3.9e-3.
#define ALPHA_CUT 1e-9f

__global__ __launch_bounds__(256) void graves_fused(
    const float* __restrict__ C,
    const float* __restrict__ context,
    const float* __restrict__ mu_tm1,
    const float* __restrict__ W1,
    const float* __restrict__ b1,
    const float* __restrict__ W2,
    const float* __restrict__ b2,
    float* __restrict__ out)
{
    const int b   = blockIdx.x;
    const int tid = threadIdx.x;

    __shared__ float xs[ME];         // C row
    __shared__ float hpart[4][64];   // split-K partials for h
    __shared__ float h_s[H];
    __shared__ float gbk_s[60];
    __shared__ float g_s[K], sig_s[K], mu_s[K];
    __shared__ float alpha_s[T];
    __shared__ float4 red[256];      // final c_t reduce
    __shared__ int   tend_s;         // dynamic truncation point for c_t

    // ---- load x = C[b] (512 contiguous floats) ----
    xs[tid]       = C[(size_t)b * ME + tid];
    xs[tid + 256] = C[(size_t)b * ME + 256 + tid];
    __syncthreads();

    // ---- h = relu(x @ W1 + b1), W1 is (512, 51) row-major ----
    {
        const int j = tid & 63;      // output index (j < 51 active)
        const int q = tid >> 6;      // split-K quarter
        float p = 0.f;
        if (j < H) {
            const int i0 = q * 128;
            #pragma unroll 8
            for (int i = 0; i < 128; ++i) {
                p += xs[i0 + i] * W1[(size_t)(i0 + i) * H + j];
            }
        }
        hpart[q][j] = p;
    }
    __syncthreads();
    if (tid < H) {
        float v = b1[tid] + hpart[0][tid] + hpart[1][tid] + hpart[2][tid] + hpart[3][tid];
        h_s[tid] = v > 0.f ? v : 0.f;
    }
    __syncthreads();

    // ---- gbk = h @ W2 + b2, W2 is (51, 60) row-major ----
    if (tid < 60) {
        float acc = b2[tid];
        #pragma unroll
        for (int i = 0; i < H; ++i) acc += h_s[i] * W2[i * 60 + tid];
        gbk_s[tid] = acc;
    }
    if (tid == 0) tend_s = 1;        // init truncation point (covered by next barrier)
    __syncthreads();

    // ---- softmax(g), exp(sig), mu update; write mu_t output ----
    if (tid < K) {
        float m = -1e30f;
        #pragma unroll
        for (int i = 0; i < K; ++i) m = fmaxf(m, gbk_s[i]);
        float s = 0.f;
        #pragma unroll
        for (int i = 0; i < K; ++i) s += expf(gbk_s[i] - m);
        g_s[tid]   = expf(gbk_s[tid] - m) / s + EPS;
        sig_s[tid] = expf(gbk_s[K + tid]) + EPS;
        float mu = mu_tm1[(size_t)b * K + tid] + ALIGN_C * expf(gbk_s[2 * K + tid]);
        mu_s[tid] = mu;
        out[(size_t)BATCH * D + (size_t)b * K + tid] = mu;  // mu_t output
    }
    __syncthreads();

    // ---- alpha[b,t] = COEF * sum_k g[k] * exp(-0.5*sig[k]*(mu[k]-t)^2) ----
    // Also track the last t with alpha > ALPHA_CUT; beyond it the c_t
    // contribution is numerically zero (Gaussians centered at mu ~ [0,3]).
    {
        int lmax = 0;
        for (int t = tid; t < T; t += 256) {
            const float ft = (float)t;
            float a = 0.f;
            #pragma unroll
            for (int k = 0; k < K; ++k) {
                float d = mu_s[k] - ft;
                a += g_s[k] * __expf(-0.5f * sig_s[k] * d * d);
            }
            a *= COEF;
            alpha_s[t] = a;
            if (a > ALPHA_CUT) lmax = t + 1;
            out[(size_t)BATCH * D + (size_t)BATCH * K + (size_t)b * T + t] = a;  // alpha output
        }
        if (lmax > 0) atomicMax(&tend_s, lmax);
    }
    __syncthreads();
    const int t_end = tend_s;

    // ---- c_t[b,d] = sum_{t<t_end} alpha[t] * context[b,t,d] ----
    // (was the 524 MB read; now only ~t_end/500 of context is touched)
    {
        const int lane = tid & 63;   // owns d = lane*4 .. lane*4+3
        const int q    = tid >> 6;   // wave owns t ≡ q (mod 4)
        const float4* ctx = (const float4*)(context + (size_t)b * T * D);
        float4 acc = make_float4(0.f, 0.f, 0.f, 0.f);
        for (int t = q; t < t_end; t += 4) {
            const float a  = alpha_s[t];           // wave-uniform broadcast
            const float4 v = ctx[t * 64 + lane];   // coalesced 1KB/wave
            acc.x += a * v.x;
            acc.y += a * v.y;
            acc.z += a * v.z;
            acc.w += a * v.w;
        }
        red[tid] = acc;
    }
    __syncthreads();
    if (tid < 64) {
        float4 a0 = red[tid];
        float4 a1 = red[tid + 64];
        float4 a2 = red[tid + 128];
        float4 a3 = red[tid + 192];
        float4 r;
        r.x = a0.x + a1.x + a2.x + a3.x;
        r.y = a0.y + a1.y + a2.y + a3.y;
        r.z = a0.z + a1.z + a2.z + a3.z;
        r.w = a0.w + a1.w + a2.w + a3.w;
        ((float4*)(out + (size_t)b * D))[tid] = r;   // c_t output
    }
}

extern "C" void kernel_launch(void* const* d_in, const int* in_sizes, int n_in,
                              void* d_out, int out_size, void* d_ws, size_t ws_size,
                              hipStream_t stream) {
    const float* C       = (const float*)d_in[0];
    const float* context = (const float*)d_in[1];
    const float* mu_tm1  = (const float*)d_in[2];
    const float* W1      = (const float*)d_in[3];
    const float* b1      = (const float*)d_in[4];
    const float* W2      = (const float*)d_in[5];
    const float* b2      = (const float*)d_in[6];
    float* out = (float*)d_out;

    graves_fused<<<BATCH, 256, 0, stream>>>(C, context, mu_tm1, W1, b1, W2, b2, out);
}